// Round 3
// baseline (145.498 us; speedup 1.0000x reference)
//
#include <hip/hip_runtime.h>
#include <hip/hip_bf16.h>

// Problem dims (AdditiveAttention_56865366999388)
#define NB 4
#define NQL 512   // query length
#define ML 512    // key/value length
#define DDIM 256  // DQ == DK == DV
#define HDIM 256  // H

static constexpr float TWO_LOG2E = 2.8853900817779268f; // 2*log2(e)
static constexpr float LOG2E     = 1.4426950408889634f;

// ---------------------------------------------------------------------------
// Kernel 1: projection + exp.
//   EqT[b][h][l] = exp2( TWO_LOG2E * sum_d q_src[b][l][d]*Wq[d][h] )  (= e^{2q})
//   EkT likewise. Stored h-major so scores kernel reads contiguous l rows.
// grid: (16, 4, 8). block 256. 32l x 64h tile, 2l x 4h per thread.
// ---------------------------------------------------------------------------
__global__ __launch_bounds__(256) void proj_kernel(
    const float* __restrict__ q_src, const float* __restrict__ k_src,
    const float* __restrict__ Wq,    const float* __restrict__ Wk,
    float* __restrict__ EqT,         float* __restrict__ EkT)
{
    const int z = blockIdx.z;
    const int b = z & 3;
    const int which = z >> 2;
    const float* __restrict__ src  = which ? k_src : q_src;
    const float* __restrict__ W    = which ? Wk    : Wq;
    float* __restrict__       outT = which ? EkT   : EqT;

    const int l0 = blockIdx.x * 32;
    const int h0 = blockIdx.y * 64;
    const int t  = threadIdx.x;
    const int tx = t & 15;   // h group (4 each)
    const int ty = t >> 4;   // l (2 each)

    __shared__ __align__(16) float sX[32][36];   // [dd][ll]
    __shared__ __align__(16) float sW[32][68];   // [dd][hh]

    float acc[2][4];
    #pragma unroll
    for (int i = 0; i < 2; i++)
        #pragma unroll
        for (int j = 0; j < 4; j++) acc[i][j] = 0.f;

    const int llA = t >> 3, dgA = t & 7;   // X: 32 l rows x 8 d-groups(4)
    const int ddB = t >> 3, hgB = t & 7;   // W: 32 d rows x 8 h-groups(8)

    for (int d0 = 0; d0 < DDIM; d0 += 32) {
        float4 xv = *(const float4*)&src[(size_t)(b * NQL + l0 + llA) * DDIM + d0 + dgA * 4];
        const float* wrow = &W[(size_t)(d0 + ddB) * HDIM + h0 + hgB * 8];
        float4 wa = ((const float4*)wrow)[0];
        float4 wb = ((const float4*)wrow)[1];
        __syncthreads();
        sX[dgA * 4 + 0][llA] = xv.x;
        sX[dgA * 4 + 1][llA] = xv.y;
        sX[dgA * 4 + 2][llA] = xv.z;
        sX[dgA * 4 + 3][llA] = xv.w;
        *(float4*)&sW[ddB][hgB * 8]     = wa;
        *(float4*)&sW[ddB][hgB * 8 + 4] = wb;
        __syncthreads();
        #pragma unroll
        for (int dd = 0; dd < 32; dd++) {
            float4 w4 = *(const float4*)&sW[dd][tx * 4];
            float2 x2 = *(const float2*)&sX[dd][ty * 2];
            acc[0][0] = fmaf(x2.x, w4.x, acc[0][0]);
            acc[0][1] = fmaf(x2.x, w4.y, acc[0][1]);
            acc[0][2] = fmaf(x2.x, w4.z, acc[0][2]);
            acc[0][3] = fmaf(x2.x, w4.w, acc[0][3]);
            acc[1][0] = fmaf(x2.y, w4.x, acc[1][0]);
            acc[1][1] = fmaf(x2.y, w4.y, acc[1][1]);
            acc[1][2] = fmaf(x2.y, w4.z, acc[1][2]);
            acc[1][3] = fmaf(x2.y, w4.w, acc[1][3]);
        }
    }

    #pragma unroll
    for (int j = 0; j < 4; j++) {
        float2 o;
        o.x = __builtin_amdgcn_exp2f(acc[0][j] * TWO_LOG2E);
        o.y = __builtin_amdgcn_exp2f(acc[1][j] * TWO_LOG2E);
        *(float2*)&outT[(size_t)(b * HDIM + h0 + tx * 4 + j) * NQL + l0 + ty * 2] = o;
    }
}

// ---------------------------------------------------------------------------
// Kernel 2: scores.
//   tanh(q+k) = 1 - 2/(e^{2q}e^{2k}+1);  S = sum_h Wv[h] - sum_h 2*Wv[h]/a,
//   a = fma(Eq,Ek,1).  Paired reciprocal across m.
// grid: (8 m-tiles, 32 n-tiles, 4 b) = 1024 blocks. block 256.
// 16n x 64m tile, 1n x 4m per thread.
// sQ transposed [nn][hh] -> b128 broadcast per 4hh; sK [hh][mm] -> b128/hh.
// ---------------------------------------------------------------------------
__global__ __launch_bounds__(256) void scores_kernel(
    const float* __restrict__ EqT, const float* __restrict__ EkT,
    const float* __restrict__ Wv, float* __restrict__ S)
{
    const int b  = blockIdx.z;
    const int m0 = blockIdx.x * 64;
    const int n0 = blockIdx.y * 16;
    const int t  = threadIdx.x;
    const int tx = t & 15;   // m group (4 m)
    const int ty = t >> 4;   // n (1 each)

    __shared__ __align__(16) float sQ[16][36];   // [nn][hh]
    __shared__ __align__(16) float sK[32][68];   // [hh][mm]
    __shared__ __align__(16) float sWV[32];

    float acc0 = 0.f, acc1 = 0.f, acc2 = 0.f, acc3 = 0.f;
    float swv = 0.f;

    const int hhA = t >> 3;       // 0..31
    const int cgA = t & 7;        // col group

    for (int h0 = 0; h0 < HDIM; h0 += 32) {
        // global reads (Eq: 2 n per thread; Ek: 8 m per thread)
        float2 qv = *(const float2*)&EqT[(size_t)(b * HDIM + h0 + hhA) * NQL + n0 + cgA * 2];
        const float* krow = &EkT[(size_t)(b * HDIM + h0 + hhA) * ML + m0 + cgA * 8];
        float4 ka = ((const float4*)krow)[0];
        float4 kb = ((const float4*)krow)[1];
        float wv_ld = (t < 32) ? Wv[h0 + t] : 0.f;
        __syncthreads();
        sQ[cgA * 2 + 0][hhA] = qv.x;     // transpose: 2-way bank alias (free)
        sQ[cgA * 2 + 1][hhA] = qv.y;
        *(float4*)&sK[hhA][cgA * 8]     = ka;
        *(float4*)&sK[hhA][cgA * 8 + 4] = kb;
        if (t < 32) sWV[t] = wv_ld;
        __syncthreads();
        #pragma unroll
        for (int g = 0; g < 8; g++) {
            float4 q4 = *(const float4*)&sQ[ty][g * 4];   // broadcast across tx
            float4 w4 = *(const float4*)&sWV[g * 4];      // broadcast
            float qs[4] = {q4.x, q4.y, q4.z, q4.w};
            float ws[4] = {w4.x, w4.y, w4.z, w4.w};
            #pragma unroll
            for (int j = 0; j < 4; j++) {
                float4 k4 = *(const float4*)&sK[g * 4 + j][tx * 4]; // 2-way (free)
                float wv = ws[j];
                swv += wv;
                const float nw2 = -2.0f * wv;
                float a0 = fmaf(qs[j], k4.x, 1.0f);   // e^{2(q+k)} + 1
                float a1 = fmaf(qs[j], k4.y, 1.0f);
                float a2 = fmaf(qs[j], k4.z, 1.0f);
                float a3 = fmaf(qs[j], k4.w, 1.0f);
                float r01 = __builtin_amdgcn_rcpf(a0 * a1);
                float r23 = __builtin_amdgcn_rcpf(a2 * a3);
                acc0 = fmaf(nw2, r01 * a1, acc0);
                acc1 = fmaf(nw2, r01 * a0, acc1);
                acc2 = fmaf(nw2, r23 * a3, acc2);
                acc3 = fmaf(nw2, r23 * a2, acc3);
            }
        }
    }

    float4 o = {swv + acc0, swv + acc1, swv + acc2, swv + acc3};
    *(float4*)&S[(size_t)(b * NQL + n0 + ty) * ML + m0 + tx * 4] = o;
}

// ---------------------------------------------------------------------------
// Kernel 3: fused softmax + AV.
// Scores are bounded (|S| <= sum|Wv| ~ 13) -> softmax without max-subtraction.
// Phase 1: exp rows of S into LDS (16n x 512m) + row sums.
// Phase 2: O[n][v] = (1/rowsum) * sum_m P[n][m]*V[m][v], V read direct from
// global (L2-resident). Lane map tx=n, ty=v-group so the 16 n-lanes share one
// V address -> 64B/load coalesced, block V traffic exactly 128 KB.
// grid: (4 v-tiles, 32 n-tiles, 4 b) = 512 blocks. block 256.
// ---------------------------------------------------------------------------
__global__ __launch_bounds__(256) void sav_kernel(
    const float* __restrict__ S, const float* __restrict__ V,
    float* __restrict__ O)
{
    const int b  = blockIdx.z;
    const int v0 = blockIdx.x * 64;
    const int n0 = blockIdx.y * 16;
    const int t  = threadIdx.x;

    __shared__ __align__(16) float sP[16][516];
    __shared__ __align__(16) float sRed[16][16];

    // ---- phase 1: staging-exp + partial row sums (row = t>>4, seg = t&15)
    const int row = t >> 4;
    const int seg = t & 15;
    {
        const float* srow = &S[(size_t)(b * NQL + n0 + row) * ML + seg * 32];
        float psum = 0.f;
        #pragma unroll
        for (int i = 0; i < 8; i++) {
            float4 sv = ((const float4*)srow)[i];
            float4 e;
            e.x = __builtin_amdgcn_exp2f(sv.x * LOG2E);
            e.y = __builtin_amdgcn_exp2f(sv.y * LOG2E);
            e.z = __builtin_amdgcn_exp2f(sv.z * LOG2E);
            e.w = __builtin_amdgcn_exp2f(sv.w * LOG2E);
            *(float4*)&sP[row][seg * 32 + i * 4] = e;
            psum += (e.x + e.y) + (e.z + e.w);
        }
        sRed[row][seg] = psum;
    }
    __syncthreads();

    // ---- phase 2: AV.  tx = n (0..15), ty = v-group (0..15)
    const int tx = t & 15;
    const int ty = t >> 4;
    float rs = 0.f;
    #pragma unroll
    for (int i = 0; i < 16; i++) rs += sRed[tx][i];   // broadcast reads
    const float inv = 1.0f / rs;

    float4 acc = {0.f, 0.f, 0.f, 0.f};
    const float* vbase = &V[(size_t)b * ML * DDIM + v0 + ty * 4];
    #pragma unroll 2
    for (int m4 = 0; m4 < 128; m4++) {
        float4 a4 = *(const float4*)&sP[tx][m4 * 4];    // 2-way bank alias
        float4 va = *(const float4*)&vbase[(size_t)(m4 * 4 + 0) * DDIM];
        float4 vb = *(const float4*)&vbase[(size_t)(m4 * 4 + 1) * DDIM];
        float4 vc = *(const float4*)&vbase[(size_t)(m4 * 4 + 2) * DDIM];
        float4 vd = *(const float4*)&vbase[(size_t)(m4 * 4 + 3) * DDIM];
        acc.x = fmaf(a4.x, va.x, acc.x);
        acc.y = fmaf(a4.x, va.y, acc.y);
        acc.z = fmaf(a4.x, va.z, acc.z);
        acc.w = fmaf(a4.x, va.w, acc.w);
        acc.x = fmaf(a4.y, vb.x, acc.x);
        acc.y = fmaf(a4.y, vb.y, acc.y);
        acc.z = fmaf(a4.y, vb.z, acc.z);
        acc.w = fmaf(a4.y, vb.w, acc.w);
        acc.x = fmaf(a4.z, vc.x, acc.x);
        acc.y = fmaf(a4.z, vc.y, acc.y);
        acc.z = fmaf(a4.z, vc.z, acc.z);
        acc.w = fmaf(a4.z, vc.w, acc.w);
        acc.x = fmaf(a4.w, vd.x, acc.x);
        acc.y = fmaf(a4.w, vd.y, acc.y);
        acc.z = fmaf(a4.w, vd.z, acc.z);
        acc.w = fmaf(a4.w, vd.w, acc.w);
    }

    float4 o;
    o.x = acc.x * inv; o.y = acc.y * inv; o.z = acc.z * inv; o.w = acc.w * inv;
    *(float4*)&O[(size_t)(b * NQL + n0 + tx) * DDIM + v0 + ty * 4] = o;
}

// ---------------------------------------------------------------------------
extern "C" void kernel_launch(void* const* d_in, const int* in_sizes, int n_in,
                              void* d_out, int out_size, void* d_ws, size_t ws_size,
                              hipStream_t stream)
{
    const float* query = (const float*)d_in[0]; // (4,512,256)
    const float* key   = (const float*)d_in[1]; // (4,512,256)
    const float* value = (const float*)d_in[2]; // (4,512,256)
    const float* Wq    = (const float*)d_in[3]; // (256,256)
    const float* Wk    = (const float*)d_in[4]; // (256,256)
    const float* Wv    = (const float*)d_in[5]; // (256,)
    float* out = (float*)d_out;                 // (4,512,256)

    // workspace layout (fp32): EqT 2MB | EkT 2MB | scores 4MB
    float* EqT = (float*)d_ws;                        // [4][256][512]
    float* EkT = EqT + (size_t)NB * HDIM * NQL;       // [4][256][512]
    float* S   = EkT + (size_t)NB * HDIM * ML;        // [4][512][512]

    dim3 gProj(NQL / 32, HDIM / 64, NB * 2);
    proj_kernel<<<gProj, 256, 0, stream>>>(query, key, Wq, Wk, EqT, EkT);

    dim3 gSc(ML / 64, NQL / 16, NB);
    scores_kernel<<<gSc, 256, 0, stream>>>(EqT, EkT, Wv, S);

    dim3 gSav(DDIM / 64, NQL / 16, NB);
    sav_kernel<<<gSav, 256, 0, stream>>>(S, value, out);
}